// Round 1
// baseline (671.236 us; speedup 1.0000x reference)
//
#include <hip/hip_runtime.h>
#include <hip/hip_bf16.h>

#define T_TOK 2048
#define HDIM  1024
#define FDIM  4096
#define NEXP  8
#define BM    128
#define BN    128
#define BK    32
#define BKP   40   // padded LDS row stride in bf16 elems (80 B = 16*5, keeps b128 aligned)

// workspace layout (bytes)
#define OFF_CNT   32
#define OFF_LT    64
#define OFF_LC    (OFF_LT + NEXP * T_TOK * 4)   // 65600
#define OFF_LG    (OFF_LC + NEXP * T_TOK * 4)   // 131136
#define OFF_HBUF  262144                        // Hbuf: 4096 x 4096 bf16 = 32 MB

typedef float f32x4 __attribute__((ext_vector_type(4)));
typedef short bf16x8 __attribute__((ext_vector_type(8)));

__device__ __forceinline__ unsigned short f2bf(float f) {
    unsigned int u = __builtin_bit_cast(unsigned int, f);
    u = (u + 0x7FFFu + ((u >> 16) & 1u)) >> 16;   // RNE
    return (unsigned short)u;
}

// ---------------- router + sparsemixer + list build ----------------
__global__ __launch_bounds__(64) void router_kernel(
    const float* __restrict__ x, const float* __restrict__ gw,
    float* __restrict__ out_logits, int* __restrict__ gcnt, int* __restrict__ cnt,
    int* __restrict__ list_t, float* __restrict__ list_c, int* __restrict__ list_g)
{
    const int t = blockIdx.x;
    const int lane = threadIdx.x;
    const float* xr = x + (size_t)t * HDIM;

    f32x4 acc0 = {0.f, 0.f, 0.f, 0.f};
    f32x4 acc1 = {0.f, 0.f, 0.f, 0.f};
    #pragma unroll
    for (int c = 0; c < 4; ++c) {
        const int h0 = (c * 64 + lane) * 4;
        const float4 xv = *(const float4*)(xr + h0);
        const float hv[4] = {xv.x, xv.y, xv.z, xv.w};
        #pragma unroll
        for (int j = 0; j < 4; ++j) {
            const f32x4 g0 = *(const f32x4*)(gw + (size_t)(h0 + j) * NEXP);
            const f32x4 g1 = *(const f32x4*)(gw + (size_t)(h0 + j) * NEXP + 4);
            acc0 += hv[j] * g0;
            acc1 += hv[j] * g1;
        }
    }
    float sv[8];
    #pragma unroll
    for (int e = 0; e < 4; ++e) { sv[e] = acc0[e]; sv[e + 4] = acc1[e]; }
    #pragma unroll
    for (int e = 0; e < 8; ++e) {
        #pragma unroll
        for (int off = 32; off > 0; off >>= 1) sv[e] += __shfl_down(sv[e], off);
    }
    if (lane == 0) {
        #pragma unroll
        for (int e = 0; e < 8; ++e) out_logits[(size_t)t * NEXP + e] = sv[e];
        // first argmax (strict > keeps first occurrence, matches jnp.argmax)
        float m1v = sv[0]; int i0 = 0;
        #pragma unroll
        for (int e = 1; e < 8; ++e) if (sv[e] > m1v) { m1v = sv[e]; i0 = e; }
        float d1 = 0.f;
        #pragma unroll
        for (int e = 0; e < 8; ++e) {
            const float fac = fmaxf(fabsf(sv[e]), m1v);
            if (!(((m1v - sv[e]) / fac) > 0.02f)) d1 += expf(sv[e] - m1v);
        }
        const float mult1 = 1.f / d1;
        // second argmax over e != i0
        float m2v = -INFINITY; int i1 = 0;
        #pragma unroll
        for (int e = 0; e < 8; ++e) if (e != i0 && sv[e] > m2v) { m2v = sv[e]; i1 = e; }
        float d2 = 0.f;
        #pragma unroll
        for (int e = 0; e < 8; ++e) {
            if (e == i0) continue;
            const float fac = fmaxf(fabsf(sv[e]), m2v);
            if (!(((m2v - sv[e]) / fac) > 0.02f)) d2 += expf(sv[e] - m2v);
        }
        const float mult2 = 1.f / d2;
        // faithful combine quirk: slot-k coefficient = weight of EXPERT k if selected
        const float c0 = (i0 == 0) ? mult1 : ((i1 == 0) ? mult2 : 0.f); // attaches to expert i0
        const float c1 = (i0 == 1) ? mult1 : ((i1 == 1) ? mult2 : 0.f); // attaches to expert i1
        if (c0 != 0.f) {
            const int pos = atomicAdd(&cnt[i0], 1);
            const int g = atomicAdd(gcnt, 1);
            list_t[i0 * T_TOK + pos] = t;
            list_c[i0 * T_TOK + pos] = c0;
            list_g[i0 * T_TOK + pos] = g;
        }
        if (c1 != 0.f) {
            const int pos = atomicAdd(&cnt[i1], 1);
            const int g = atomicAdd(gcnt, 1);
            list_t[i1 * T_TOK + pos] = t;
            list_c[i1 * T_TOK + pos] = c1;
            list_g[i1 * T_TOK + pos] = g;
        }
    }
}

// ---------------- stage 1: H = silu(X*W1) .* (X*W3) ----------------
__global__ __launch_bounds__(256, 2) void stage1_kernel(
    const float* __restrict__ x, const float* __restrict__ w1, const float* __restrict__ w3,
    const int* __restrict__ cnt, const int* __restrict__ list_t, const int* __restrict__ list_g,
    unsigned short* __restrict__ Hbuf)
{
    const int e  = blockIdx.z;
    const int tc = blockIdx.y;
    const int fc = blockIdx.x;
    const int ne = cnt[e];
    const int base = tc * BM;
    if (base >= ne) return;
    const int f0 = fc * BN;

    __shared__ unsigned short sA[BM][BKP];
    __shared__ unsigned short sB1[BN][BKP];
    __shared__ unsigned short sB2[BN][BKP];
    __shared__ int s_tok[BM];
    __shared__ int s_g[BM];

    const int tid = threadIdx.x;
    if (tid < BM) {
        const int idx = base + tid;
        const bool v = idx < ne;
        s_tok[tid] = v ? list_t[e * T_TOK + idx] : -1;
        s_g[tid]   = v ? list_g[e * T_TOK + idx] : -1;
    }

    const int wid  = tid >> 6;
    const int lane = tid & 63;
    const int wm   = (wid >> 1) * 64;
    const int wn   = (wid & 1) * 64;
    const int l15  = lane & 15;
    const int l4   = lane >> 4;

    f32x4 accG[4][4], accU[4][4];
    #pragma unroll
    for (int i = 0; i < 4; ++i)
        #pragma unroll
        for (int j = 0; j < 4; ++j) {
            accG[i][j] = f32x4{0.f, 0.f, 0.f, 0.f};
            accU[i][j] = f32x4{0.f, 0.f, 0.f, 0.f};
        }

    const float* __restrict__ w1e = w1 + (size_t)e * HDIM * FDIM + f0;
    const float* __restrict__ w3e = w3 + (size_t)e * HDIM * FDIM + f0;

    __syncthreads();

    for (int k0 = 0; k0 < HDIM; k0 += BK) {
        // stage A: [128 tokens x 32 k] fp32 -> bf16 (rows gathered)
        #pragma unroll
        for (int i = 0; i < 4; ++i) {
            const int idx = tid + i * 256;
            const int m = idx >> 3;
            const int q = idx & 7;
            const int tok = s_tok[m];
            float4 v = make_float4(0.f, 0.f, 0.f, 0.f);
            if (tok >= 0) v = *(const float4*)(x + (size_t)tok * HDIM + k0 + q * 4);
            uint2 pk;
            pk.x = (unsigned)f2bf(v.x) | ((unsigned)f2bf(v.y) << 16);
            pk.y = (unsigned)f2bf(v.z) | ((unsigned)f2bf(v.w) << 16);
            *(uint2*)(&sA[m][q * 4]) = pk;
        }
        // stage B1/B2: w[k0..k0+32][f0..f0+128] transposed into [n][k]
        #pragma unroll
        for (int i = 0; i < 4; ++i) {
            const int idx = tid + i * 256;
            const int f  = idx & 127;
            const int kq = idx >> 7;
            const float* p1 = w1e + (size_t)(k0 + kq * 4) * FDIM + f;
            const float* p3 = w3e + (size_t)(k0 + kq * 4) * FDIM + f;
            uint2 pk;
            pk.x = (unsigned)f2bf(p1[0]) | ((unsigned)f2bf(p1[FDIM]) << 16);
            pk.y = (unsigned)f2bf(p1[2 * FDIM]) | ((unsigned)f2bf(p1[3 * FDIM]) << 16);
            *(uint2*)(&sB1[f][kq * 4]) = pk;
            pk.x = (unsigned)f2bf(p3[0]) | ((unsigned)f2bf(p3[FDIM]) << 16);
            pk.y = (unsigned)f2bf(p3[2 * FDIM]) | ((unsigned)f2bf(p3[3 * FDIM]) << 16);
            *(uint2*)(&sB2[f][kq * 4]) = pk;
        }
        __syncthreads();

        bf16x8 af[4], b1[4], b2[4];
        #pragma unroll
        for (int mi = 0; mi < 4; ++mi)
            af[mi] = *(const bf16x8*)(&sA[wm + mi * 16 + l15][l4 * 8]);
        #pragma unroll
        for (int ni = 0; ni < 4; ++ni) {
            b1[ni] = *(const bf16x8*)(&sB1[wn + ni * 16 + l15][l4 * 8]);
            b2[ni] = *(const bf16x8*)(&sB2[wn + ni * 16 + l15][l4 * 8]);
        }
        #pragma unroll
        for (int mi = 0; mi < 4; ++mi)
            #pragma unroll
            for (int ni = 0; ni < 4; ++ni) {
                accG[mi][ni] = __builtin_amdgcn_mfma_f32_16x16x32_bf16(af[mi], b1[ni], accG[mi][ni], 0, 0, 0);
                accU[mi][ni] = __builtin_amdgcn_mfma_f32_16x16x32_bf16(af[mi], b2[ni], accU[mi][ni], 0, 0, 0);
            }
        __syncthreads();
    }

    // epilogue: H = silu(G)*U -> Hbuf rows (bf16)
    #pragma unroll
    for (int mi = 0; mi < 4; ++mi) {
        #pragma unroll
        for (int j = 0; j < 4; ++j) {
            const int row = wm + mi * 16 + l4 * 4 + j;
            const int g = s_g[row];
            if (g < 0) continue;
            unsigned short* dst = Hbuf + (size_t)g * FDIM + f0 + wn + l15;
            #pragma unroll
            for (int ni = 0; ni < 4; ++ni) {
                const float gv = accG[mi][ni][j];
                const float uv = accU[mi][ni][j];
                const float hv = (gv / (1.f + expf(-gv))) * uv;
                dst[ni * 16] = f2bf(hv);
            }
        }
    }
}

// ---------------- stage 2: out += coef * (H @ W2) ----------------
__global__ __launch_bounds__(256, 2) void stage2_kernel(
    const float* __restrict__ w2, const int* __restrict__ cnt,
    const int* __restrict__ list_t, const float* __restrict__ list_c,
    const int* __restrict__ list_g, const unsigned short* __restrict__ Hbuf,
    float* __restrict__ outp)
{
    const int e  = blockIdx.z;
    const int tc = blockIdx.y;
    const int nc = blockIdx.x;
    const int ne = cnt[e];
    const int base = tc * BM;
    if (base >= ne) return;
    const int n0 = nc * BN;

    __shared__ unsigned short sA[BM][BKP];
    __shared__ unsigned short sB[BN][BKP];
    __shared__ int   s_tok[BM];
    __shared__ float s_c[BM];
    __shared__ int   s_g[BM];

    const int tid = threadIdx.x;
    if (tid < BM) {
        const int idx = base + tid;
        const bool v = idx < ne;
        s_tok[tid] = v ? list_t[e * T_TOK + idx] : -1;
        s_c[tid]   = v ? list_c[e * T_TOK + idx] : 0.f;
        s_g[tid]   = v ? list_g[e * T_TOK + idx] : -1;
    }

    const int wid  = tid >> 6;
    const int lane = tid & 63;
    const int wm   = (wid >> 1) * 64;
    const int wn   = (wid & 1) * 64;
    const int l15  = lane & 15;
    const int l4   = lane >> 4;

    f32x4 acc[4][4];
    #pragma unroll
    for (int i = 0; i < 4; ++i)
        #pragma unroll
        for (int j = 0; j < 4; ++j) acc[i][j] = f32x4{0.f, 0.f, 0.f, 0.f};

    const float* __restrict__ w2e = w2 + (size_t)e * FDIM * HDIM + n0;

    __syncthreads();

    for (int k0 = 0; k0 < FDIM; k0 += BK) {
        // stage A from Hbuf (already bf16): 128 rows x 32 k
        #pragma unroll
        for (int i = 0; i < 2; ++i) {
            const int idx = tid + i * 256;
            const int m = idx >> 2;
            const int q = idx & 3;
            const int g = s_g[m];
            uint4 v = make_uint4(0u, 0u, 0u, 0u);
            if (g >= 0) v = *(const uint4*)(Hbuf + (size_t)g * FDIM + k0 + q * 8);
            *(uint4*)(&sA[m][q * 8]) = v;
        }
        // stage B: w2[k0..+32][n0..+128] transposed into [n][k]
        #pragma unroll
        for (int i = 0; i < 4; ++i) {
            const int idx = tid + i * 256;
            const int n  = idx & 127;
            const int kq = idx >> 7;
            const float* p = w2e + (size_t)(k0 + kq * 4) * HDIM + n;
            uint2 pk;
            pk.x = (unsigned)f2bf(p[0]) | ((unsigned)f2bf(p[HDIM]) << 16);
            pk.y = (unsigned)f2bf(p[2 * HDIM]) | ((unsigned)f2bf(p[3 * HDIM]) << 16);
            *(uint2*)(&sB[n][kq * 4]) = pk;
        }
        __syncthreads();

        bf16x8 af[4], bf[4];
        #pragma unroll
        for (int mi = 0; mi < 4; ++mi)
            af[mi] = *(const bf16x8*)(&sA[wm + mi * 16 + l15][l4 * 8]);
        #pragma unroll
        for (int ni = 0; ni < 4; ++ni)
            bf[ni] = *(const bf16x8*)(&sB[wn + ni * 16 + l15][l4 * 8]);
        #pragma unroll
        for (int mi = 0; mi < 4; ++mi)
            #pragma unroll
            for (int ni = 0; ni < 4; ++ni)
                acc[mi][ni] = __builtin_amdgcn_mfma_f32_16x16x32_bf16(af[mi], bf[ni], acc[mi][ni], 0, 0, 0);
        __syncthreads();
    }

    // epilogue: final[tok, col] += coef * out
    #pragma unroll
    for (int mi = 0; mi < 4; ++mi) {
        #pragma unroll
        for (int j = 0; j < 4; ++j) {
            const int row = wm + mi * 16 + l4 * 4 + j;
            const int tok = s_tok[row];
            if (tok < 0) continue;
            const float c = s_c[row];
            float* dst = outp + (size_t)tok * HDIM + n0 + wn + l15;
            #pragma unroll
            for (int ni = 0; ni < 4; ++ni)
                atomicAdd(dst + ni * 16, c * acc[mi][ni][j]);
        }
    }
}

extern "C" void kernel_launch(void* const* d_in, const int* in_sizes, int n_in,
                              void* d_out, int out_size, void* d_ws, size_t ws_size,
                              hipStream_t stream) {
    const float* hs = (const float*)d_in[0];
    const float* gw = (const float*)d_in[1];
    const float* w1 = (const float*)d_in[2];
    const float* w3 = (const float*)d_in[3];
    const float* w2 = (const float*)d_in[4];
    float* outp = (float*)d_out;
    float* out_logits = outp + (size_t)T_TOK * HDIM;

    char* ws = (char*)d_ws;
    int*   gcnt = (int*)ws;
    int*   cnt  = (int*)(ws + OFF_CNT);
    int*   lt   = (int*)(ws + OFF_LT);
    float* lc   = (float*)(ws + OFF_LC);
    int*   lg   = (int*)(ws + OFF_LG);
    unsigned short* Hbuf = (unsigned short*)(ws + OFF_HBUF);

    hipMemsetAsync(d_ws, 0, 64, stream);                                   // gcnt + cnt
    hipMemsetAsync(d_out, 0, (size_t)T_TOK * HDIM * sizeof(float), stream); // final accum buffer

    router_kernel<<<T_TOK, 64, 0, stream>>>(hs, gw, out_logits, gcnt, cnt, lt, lc, lg);
    stage1_kernel<<<dim3(FDIM / BN, T_TOK / BM, NEXP), 256, 0, stream>>>(hs, w1, w3, cnt, lt, lg, Hbuf);
    stage2_kernel<<<dim3(HDIM / BN, T_TOK / BM, NEXP), 256, 0, stream>>>(w2, cnt, lt, lc, lg, Hbuf, outp);
}